// Round 4
// baseline (3823.905 us; speedup 1.0000x reference)
//
#include <hip/hip_runtime.h>

#if __has_builtin(__builtin_amdgcn_exp2f)
#define EXP2F(x) __builtin_amdgcn_exp2f(x)
#else
#define EXP2F(x) exp2f(x)
#endif
#if __has_builtin(__builtin_amdgcn_rcpf)
#define RCPF(x) __builtin_amdgcn_rcpf(x)
#else
#define RCPF(x) (1.0f / (x))
#endif

namespace {

constexpr int B_ = 2048, T_ = 512, D_ = 8, H_ = 20, L_ = 10;
constexpr int NB   = 8;         // batches per block -> grid = 2048/8 = 256 (1 block/CU)
constexpr int NW   = L_;        // 10 waves; wave w = layer w
constexpr int PADR = 24;        // padded h row (floats): 96B, 16B-aligned
constexpr int NTHR = NW * 64;   // 640

#define LD4(p)  (*reinterpret_cast<const float4*>(p))

// 4 FMAs accumulating quad wq * quad vq into scalar acc
#define FMA4(acc, wq, vq)                  \
    acc = fmaf((wq).x, (vq).x, acc);       \
    acc = fmaf((wq).y, (vq).y, acc);       \
    acc = fmaf((wq).z, (vq).z, acc);       \
    acc = fmaf((wq).w, (vq).w, acc);

// 20-wide dot: 5 weight quads * 5 value quads
#define DOT20(acc, w0, w1, w2, w3q, w4, v0, v1, v2, v3q, v4) \
    FMA4(acc, w0, v0) FMA4(acc, w1, v1) FMA4(acc, w2, v2)    \
    FMA4(acc, w3q, v3q) FMA4(acc, w4, v4)

__device__ __forceinline__ float tanh_fast(float x) {
    // tanh(x) = 1 - 2/(1+e^{2x}); e^{2x}=2^(x*2*log2 e). Saturates w/o NaN.
    float e = EXP2F(x * 2.8853900817779268f);
    return fmaf(-2.0f, RCPF(1.0f + e), 1.0f);
}

// Wavefront over (t, layer): diagonal c -> wave w computes layer w at t=c-w
// for 8 batches. Lane (bs=lane>>3, jo=lane&7) computes hidden rows
// {jo, jo+8, 16+(jo&3)}; lanes jo>=4 duplicate rows 16..19 and skip the
// write. All weights in NAMED float4 VGPRs (no arrays -> no SROA failure,
// R2/R3 lesson: VGPR_Count 64/80 proved arrays went to scratch).
// launch_bounds(640,3): VGPR budget 170 (a 10-wave block needs 3 waves on
// two SIMDs: 3*170 <= 512). One barrier per diagonal.
// MLP head: stage1 (fc+relu+l2-scale) on wave c%10 at lag 10, fc_w from LDS
// broadcast; stage2 (sum+store) on wave (c+4)%10 at lag 11.
__global__ __launch_bounds__(NTHR, 3) void rnn_wavefront(
    const float* __restrict__ x,      // [B,T,8]
    const float* __restrict__ w_ih0,  // [20,8]
    const float* __restrict__ w_ih,   // [9,20,20]
    const float* __restrict__ w_hh,   // [10,20,20]
    const float* __restrict__ b_ih,   // [10,20]
    const float* __restrict__ b_hh,   // [10,20]
    const float* __restrict__ fc_w,   // [20,20]
    const float* __restrict__ fc_b,   // [20]
    const float* __restrict__ l2_w,   // [1,20]
    const float* __restrict__ l2_b,   // [1]
    float* __restrict__ out)          // [B,T,1] flat
{
    __shared__ __align__(16) float h_buf[2][L_][NB][PADR];  // 15360 B
    __shared__ __align__(16) float p_buf[2][NB][8];         //   512 B
    __shared__ __align__(16) float fcw_s[H_][H_];           //  1600 B

    const int tid  = threadIdx.x;
    const int w    = tid >> 6;           // wave = layer 0..9
    const int lane = tid & 63;
    const int bs   = lane >> 3;          // batch slot 0..7
    const int jo   = lane & 7;           // row group 0..7
    const int r0 = jo, r1 = jo + 8, r2 = 16 + (jo & 3);
    const bool w3 = (jo < 4);            // this lane owns row r2
    const int bg = blockIdx.x * NB + bs; // < 2048 always (256*8 = 2048)

    // zero h history (h0 = 0, both parities) + stage fc_w
    for (int i = tid; i < 2 * L_ * NB * PADR; i += NTHR)
        (&h_buf[0][0][0][0])[i] = 0.f;
    for (int i = tid; i < H_ * H_; i += NTHR)
        fcw_s[i / H_][i % H_] = fc_w[i];

    // ---- weights: 30 named float4 (120 VGPRs), resident all kernel ----
    float4 wi00, wi01, wi02, wi03, wi04;
    float4 wi10, wi11, wi12, wi13, wi14;
    float4 wi20, wi21, wi22, wi23, wi24;
    float4 wh00, wh01, wh02, wh03, wh04;
    float4 wh10, wh11, wh12, wh13, wh14;
    float4 wh20, wh21, wh22, wh23, wh24;
    const float4 z4 = make_float4(0.f, 0.f, 0.f, 0.f);
    if (w == 0) {
        const float* p0 = w_ih0 + r0 * D_;   // rows are 32B, 16B-aligned
        const float* p1 = w_ih0 + r1 * D_;
        const float* p2 = w_ih0 + r2 * D_;
        wi00 = LD4(p0); wi01 = LD4(p0 + 4); wi02 = z4; wi03 = z4; wi04 = z4;
        wi10 = LD4(p1); wi11 = LD4(p1 + 4); wi12 = z4; wi13 = z4; wi14 = z4;
        wi20 = LD4(p2); wi21 = LD4(p2 + 4); wi22 = z4; wi23 = z4; wi24 = z4;
    } else {
        const float* p0 = w_ih + ((w - 1) * H_ + r0) * H_;  // 80B rows, aligned
        const float* p1 = w_ih + ((w - 1) * H_ + r1) * H_;
        const float* p2 = w_ih + ((w - 1) * H_ + r2) * H_;
        wi00 = LD4(p0); wi01 = LD4(p0+4); wi02 = LD4(p0+8); wi03 = LD4(p0+12); wi04 = LD4(p0+16);
        wi10 = LD4(p1); wi11 = LD4(p1+4); wi12 = LD4(p1+8); wi13 = LD4(p1+12); wi14 = LD4(p1+16);
        wi20 = LD4(p2); wi21 = LD4(p2+4); wi22 = LD4(p2+8); wi23 = LD4(p2+12); wi24 = LD4(p2+16);
    }
    {
        const float* q0 = w_hh + (w * H_ + r0) * H_;
        const float* q1 = w_hh + (w * H_ + r1) * H_;
        const float* q2 = w_hh + (w * H_ + r2) * H_;
        wh00 = LD4(q0); wh01 = LD4(q0+4); wh02 = LD4(q0+8); wh03 = LD4(q0+12); wh04 = LD4(q0+16);
        wh10 = LD4(q1); wh11 = LD4(q1+4); wh12 = LD4(q1+8); wh13 = LD4(q1+12); wh14 = LD4(q1+16);
        wh20 = LD4(q2); wh21 = LD4(q2+4); wh22 = LD4(q2+8); wh23 = LD4(q2+12); wh24 = LD4(q2+16);
    }
    const float bi0 = b_ih[w * H_ + r0] + b_hh[w * H_ + r0];
    const float bi1 = b_ih[w * H_ + r1] + b_hh[w * H_ + r1];
    const float bi2 = b_ih[w * H_ + r2] + b_hh[w * H_ + r2];

    __syncthreads();

    const int NDIAG = T_ + NW + 1;  // 523: last cell c=520, stage2 tail c=522
    for (int c = 0; c < NDIAG; ++c) {
        const int cur = c & 1, prv = cur ^ 1;
        const int t = c - w;

        // ---- RNN cell ----
        if ((unsigned)t < (unsigned)T_) {
            float a0 = bi0, a1 = bi1, a2 = bi2;
            if (w == 0) {
                const float* xp = x + ((size_t)bg * T_ + t) * D_;
                float4 xa = LD4(xp), xb = LD4(xp + 4);
                FMA4(a0, wi00, xa) FMA4(a0, wi01, xb)
                FMA4(a1, wi10, xa) FMA4(a1, wi11, xb)
                FMA4(a2, wi20, xa) FMA4(a2, wi21, xb)
            } else {
                const float* ip = &h_buf[prv][w - 1][bs][0];
                float4 v0 = LD4(ip), v1 = LD4(ip+4), v2 = LD4(ip+8),
                       v3 = LD4(ip+12), v4 = LD4(ip+16);
                DOT20(a0, wi00, wi01, wi02, wi03, wi04, v0, v1, v2, v3, v4)
                DOT20(a1, wi10, wi11, wi12, wi13, wi14, v0, v1, v2, v3, v4)
                DOT20(a2, wi20, wi21, wi22, wi23, wi24, v0, v1, v2, v3, v4)
            }
            const float* hp = &h_buf[prv][w][bs][0];
            float4 u0 = LD4(hp), u1 = LD4(hp+4), u2 = LD4(hp+8),
                   u3 = LD4(hp+12), u4 = LD4(hp+16);
            DOT20(a0, wh00, wh01, wh02, wh03, wh04, u0, u1, u2, u3, u4)
            DOT20(a1, wh10, wh11, wh12, wh13, wh14, u0, u1, u2, u3, u4)
            DOT20(a2, wh20, wh21, wh22, wh23, wh24, u0, u1, u2, u3, u4)
            h_buf[cur][w][bs][r0] = tanh_fast(a0);
            h_buf[cur][w][bs][r1] = tanh_fast(a1);
            if (w3) h_buf[cur][w][bs][r2] = tanh_fast(a2);
        }

        // ---- head stage 1: th = c-10, rotating wave c%10 ----
        const int th = c - NW;
        if ((unsigned)th < (unsigned)T_ && w == (c % NW)) {
            const float* hv = &h_buf[prv][L_ - 1][bs][0];
            float4 h0 = LD4(hv), h1 = LD4(hv+4), h2 = LD4(hv+8),
                   h3 = LD4(hv+12), h4 = LD4(hv+16);
            float d0 = fc_b[r0], d1 = fc_b[r1], d2 = fc_b[r2];
            {
                const float* f = &fcw_s[r0][0];
                float4 f0 = LD4(f), f1 = LD4(f+4), f2 = LD4(f+8),
                       f3 = LD4(f+12), f4 = LD4(f+16);
                DOT20(d0, f0, f1, f2, f3, f4, h0, h1, h2, h3, h4)
            }
            {
                const float* f = &fcw_s[r1][0];
                float4 f0 = LD4(f), f1 = LD4(f+4), f2 = LD4(f+8),
                       f3 = LD4(f+12), f4 = LD4(f+16);
                DOT20(d1, f0, f1, f2, f3, f4, h0, h1, h2, h3, h4)
            }
            {
                const float* f = &fcw_s[r2][0];
                float4 f0 = LD4(f), f1 = LD4(f+4), f2 = LD4(f+8),
                       f3 = LD4(f+12), f4 = LD4(f+16);
                DOT20(d2, f0, f1, f2, f3, f4, h0, h1, h2, h3, h4)
            }
            const float l2w0 = l2_w[r0], l2w1 = l2_w[r1];
            const float l2w2 = w3 ? l2_w[r2] : 0.f;  // jo>=4 dup rows 16..19
            float pv = l2w0 * fmaxf(d0, 0.f) + l2w1 * fmaxf(d1, 0.f)
                     + l2w2 * fmaxf(d2, 0.f);
            p_buf[cur][bs][jo] = pv;
        }

        // ---- head stage 2: th2 = c-11, rotating wave (c+4)%10 ----
        const int th2 = c - NW - 1;
        if ((unsigned)th2 < (unsigned)T_ && w == ((c + 4) % NW) && lane < NB) {
            const float* pp = &p_buf[prv][lane][0];
            float4 q0 = LD4(pp), q1 = LD4(pp + 4);
            float s = l2_b[0] + ((q0.x + q0.y) + (q0.z + q0.w))
                              + ((q1.x + q1.y) + (q1.z + q1.w));
            out[(size_t)(blockIdx.x * NB + lane) * T_ + th2] = s;
        }

        __syncthreads();  // publish cur writes; protect prv for next diagonal
    }
}

}  // namespace

extern "C" void kernel_launch(void* const* d_in, const int* in_sizes, int n_in,
                              void* d_out, int out_size, void* d_ws, size_t ws_size,
                              hipStream_t stream) {
    const float* x     = (const float*)d_in[0];
    const float* w_ih0 = (const float*)d_in[1];
    const float* w_ih  = (const float*)d_in[2];
    const float* w_hh  = (const float*)d_in[3];
    const float* b_ih  = (const float*)d_in[4];
    const float* b_hh  = (const float*)d_in[5];
    const float* fc_w  = (const float*)d_in[6];
    const float* fc_b  = (const float*)d_in[7];
    const float* l2_w  = (const float*)d_in[8];
    const float* l2_b  = (const float*)d_in[9];
    float* out = (float*)d_out;

    const int grid = B_ / NB;  // 256 = one block per CU
    hipLaunchKernelGGL(rnn_wavefront, dim3(grid), dim3(NTHR), 0, stream,
                       x, w_ih0, w_ih, w_hh, b_ih, b_hh, fc_w, fc_b,
                       l2_w, l2_b, out);
}

// Round 5
// 2797.678 us; speedup vs baseline: 1.3668x; 1.3668x over previous
//
#include <hip/hip_runtime.h>

#if __has_builtin(__builtin_amdgcn_exp2f)
#define EXP2F(x) __builtin_amdgcn_exp2f(x)
#else
#define EXP2F(x) exp2f(x)
#endif
#if __has_builtin(__builtin_amdgcn_rcpf)
#define RCPF(x) __builtin_amdgcn_rcpf(x)
#else
#define RCPF(x) (1.0f / (x))
#endif

namespace {

constexpr int B_ = 2048, T_ = 512, D_ = 8, H_ = 20, L_ = 10;
constexpr int NB   = 8;         // batches per block -> grid = 2048/8 = 256
constexpr int NW   = L_;        // 10 waves; wave w = layer w
constexpr int PADR = 24;        // padded h row: 96B, 16B-aligned
constexpr int NTHR = NW * 64;   // 640

typedef float f32x4 __attribute__((ext_vector_type(4)));

#define LD4(p)   (*reinterpret_cast<const f32x4*>(p))
#define PIN(q)   asm volatile("" : "+v"(q))   // def becomes opaque: no remat/sink

// 4 FMAs: quad wq * quad vq -> scalar acc
#define FMA4(acc, wq, vq)                    \
    acc = fmaf((wq)[0], (vq)[0], acc);       \
    acc = fmaf((wq)[1], (vq)[1], acc);       \
    acc = fmaf((wq)[2], (vq)[2], acc);       \
    acc = fmaf((wq)[3], (vq)[3], acc);

// one streamed quad feeding all 3 row-accumulators
#define STEP3(q, wA, wB, wC)  { f32x4 _t = q; \
    FMA4(a0, wA, _t) FMA4(a1, wB, _t) FMA4(a2, wC, _t) }

__device__ __forceinline__ float tanh_fast(float x) {
    // tanh(x) = 1 - 2/(1+e^{2x}); e^{2x}=2^(x*2*log2 e). Saturates w/o NaN.
    float e = EXP2F(x * 2.8853900817779268f);
    return fmaf(-2.0f, RCPF(1.0f + e), 1.0f);
}

// Wavefront over (t,layer): diagonal c -> wave w computes layer w at t=c-w,
// 8 batches/block, grid=256 (exactly 1 block/CU: perfect balance).
// Lane (bs=lane>>3, jo=lane&7) owns rows {jo, jo+8, 16+(jo&3)}; jo>=4
// duplicates rows 16..19 (uniform code) and skips the write/l2-contribution.
// Weights: 30 ext-vector quads, asm-PINNED after load so the backend cannot
// re-materialize the loads per-iteration (R3: VGPR=80, remat -> L2 reads) or
// scratch-spill them (R4: VGPR=84, 9.8GB HBM scratch). LDS temps streamed
// one quad at a time to keep demand ~150 < 170 (launchable cap for 10-wave
// blocks). Head on rotating waves {2,3,6,7} (2-wave SIMDs if wave%4 maps).
__global__ __launch_bounds__(NTHR)
__attribute__((amdgpu_waves_per_eu(2, 3)))
void rnn_wavefront(
    const float* __restrict__ x,      // [B,T,8]
    const float* __restrict__ w_ih0,  // [20,8]
    const float* __restrict__ w_ih,   // [9,20,20]
    const float* __restrict__ w_hh,   // [10,20,20]
    const float* __restrict__ b_ih,   // [10,20]
    const float* __restrict__ b_hh,   // [10,20]
    const float* __restrict__ fc_w,   // [20,20]
    const float* __restrict__ fc_b,   // [20]
    const float* __restrict__ l2_w,   // [1,20]
    const float* __restrict__ l2_b,   // [1]
    float* __restrict__ out)          // [B,T,1] flat
{
    __shared__ __align__(16) float h_buf[2][L_][NB][PADR];  // 15360 B
    __shared__ __align__(16) float p_buf[2][NB][8];         //   512 B
    __shared__ __align__(16) float fcw_s[H_][H_];           //  1600 B
    __shared__ float fcb_s[H_], l2w_s[H_], l2b_s;

    const int tid  = threadIdx.x;
    const int w    = tid >> 6;           // wave = layer 0..9
    const int lane = tid & 63;
    const int bs   = lane >> 3;          // batch slot 0..7
    const int jo   = lane & 7;           // row group 0..7
    const int r0 = jo, r1 = jo + 8, r2 = 16 + (jo & 3);
    const bool w3 = (jo < 4);            // lane owns row r2 (jo>=4: duplicate)
    const int bg = blockIdx.x * NB + bs; // < 2048 always

    // zero h history (h0 = 0, both parities); stage head weights
    for (int i = tid; i < 2 * L_ * NB * PADR; i += NTHR)
        (&h_buf[0][0][0][0])[i] = 0.f;
    if (tid < 400)      fcw_s[tid / H_][tid % H_] = fc_w[tid];
    else if (tid < 420) fcb_s[tid - 400] = fc_b[tid - 400];
    else if (tid < 440) l2w_s[tid - 420] = l2_w[tid - 420];
    else if (tid == 440) l2b_s = l2_b[0];

    // ---- weights: 30 pinned quads (120 VGPRs), resident all kernel ----
    f32x4 wi00, wi01, wi02, wi03, wi04;
    f32x4 wi10, wi11, wi12, wi13, wi14;
    f32x4 wi20, wi21, wi22, wi23, wi24;
    f32x4 wh00, wh01, wh02, wh03, wh04;
    f32x4 wh10, wh11, wh12, wh13, wh14;
    f32x4 wh20, wh21, wh22, wh23, wh24;
    const f32x4 z4 = {0.f, 0.f, 0.f, 0.f};
    if (w == 0) {
        const float* p0 = w_ih0 + r0 * D_;   // 32B rows, 16B-aligned
        const float* p1 = w_ih0 + r1 * D_;
        const float* p2 = w_ih0 + r2 * D_;
        wi00 = LD4(p0); wi01 = LD4(p0 + 4); wi02 = z4; wi03 = z4; wi04 = z4;
        wi10 = LD4(p1); wi11 = LD4(p1 + 4); wi12 = z4; wi13 = z4; wi14 = z4;
        wi20 = LD4(p2); wi21 = LD4(p2 + 4); wi22 = z4; wi23 = z4; wi24 = z4;
    } else {
        const float* p0 = w_ih + ((w - 1) * H_ + r0) * H_;  // 80B rows
        const float* p1 = w_ih + ((w - 1) * H_ + r1) * H_;
        const float* p2 = w_ih + ((w - 1) * H_ + r2) * H_;
        wi00 = LD4(p0); wi01 = LD4(p0+4); wi02 = LD4(p0+8); wi03 = LD4(p0+12); wi04 = LD4(p0+16);
        wi10 = LD4(p1); wi11 = LD4(p1+4); wi12 = LD4(p1+8); wi13 = LD4(p1+12); wi14 = LD4(p1+16);
        wi20 = LD4(p2); wi21 = LD4(p2+4); wi22 = LD4(p2+8); wi23 = LD4(p2+12); wi24 = LD4(p2+16);
    }
    {
        const float* q0 = w_hh + (w * H_ + r0) * H_;
        const float* q1 = w_hh + (w * H_ + r1) * H_;
        const float* q2 = w_hh + (w * H_ + r2) * H_;
        wh00 = LD4(q0); wh01 = LD4(q0+4); wh02 = LD4(q0+8); wh03 = LD4(q0+12); wh04 = LD4(q0+16);
        wh10 = LD4(q1); wh11 = LD4(q1+4); wh12 = LD4(q1+8); wh13 = LD4(q1+12); wh14 = LD4(q1+16);
        wh20 = LD4(q2); wh21 = LD4(q2+4); wh22 = LD4(q2+8); wh23 = LD4(q2+12); wh24 = LD4(q2+16);
    }
    float bi0 = b_ih[w * H_ + r0] + b_hh[w * H_ + r0];
    float bi1 = b_ih[w * H_ + r1] + b_hh[w * H_ + r1];
    float bi2 = b_ih[w * H_ + r2] + b_hh[w * H_ + r2];

    PIN(wi00); PIN(wi01); PIN(wi02); PIN(wi03); PIN(wi04);
    PIN(wi10); PIN(wi11); PIN(wi12); PIN(wi13); PIN(wi14);
    PIN(wi20); PIN(wi21); PIN(wi22); PIN(wi23); PIN(wi24);
    PIN(wh00); PIN(wh01); PIN(wh02); PIN(wh03); PIN(wh04);
    PIN(wh10); PIN(wh11); PIN(wh12); PIN(wh13); PIN(wh14);
    PIN(wh20); PIN(wh21); PIN(wh22); PIN(wh23); PIN(wh24);
    asm volatile("" : "+v"(bi0), "+v"(bi1), "+v"(bi2));

    __syncthreads();

    const int NDIAG = T_ + NW + 1;  // 523: last cell c=520, stage2 tail c=522
    for (int c = 0; c < NDIAG; ++c) {
        const int cur = c & 1, prv = cur ^ 1;
        const int t = c - w;  // wave-uniform

        // ---- RNN cell ----
        if ((unsigned)t < (unsigned)T_) {
            float a0 = bi0, a1 = bi1, a2 = bi2;
            if (w == 0) {
                const float* xp = x + ((size_t)bg * T_ + t) * D_;
                STEP3(LD4(xp),     wi00, wi10, wi20)
                STEP3(LD4(xp + 4), wi01, wi11, wi21)
            } else {
                const float* ip = &h_buf[prv][w - 1][bs][0];
                STEP3(LD4(ip),      wi00, wi10, wi20)
                STEP3(LD4(ip + 4),  wi01, wi11, wi21)
                STEP3(LD4(ip + 8),  wi02, wi12, wi22)
                STEP3(LD4(ip + 12), wi03, wi13, wi23)
                STEP3(LD4(ip + 16), wi04, wi14, wi24)
            }
            const float* hp = &h_buf[prv][w][bs][0];
            STEP3(LD4(hp),      wh00, wh10, wh20)
            STEP3(LD4(hp + 4),  wh01, wh11, wh21)
            STEP3(LD4(hp + 8),  wh02, wh12, wh22)
            STEP3(LD4(hp + 12), wh03, wh13, wh23)
            STEP3(LD4(hp + 16), wh04, wh14, wh24)
            h_buf[cur][w][bs][r0] = tanh_fast(a0);
            h_buf[cur][w][bs][r1] = tanh_fast(a1);
            if (w3) h_buf[cur][w][bs][r2] = tanh_fast(a2);
        }

        // head-wave rotation over {2,3,6,7}
        const int m1 = c & 3;
        const int hw1 = 2 + (m1 & 1) + ((m1 & 2) << 1);
        const int m2 = (c + 2) & 3;
        const int hw2 = 2 + (m2 & 1) + ((m2 & 2) << 1);

        // ---- head stage 1: th = c-10 ----
        const int th = c - NW;
        if ((unsigned)th < (unsigned)T_ && w == hw1) {
            const float* hv = &h_buf[prv][L_ - 1][bs][0];
            float d0 = fcb_s[r0], d1 = fcb_s[r1], d2 = fcb_s[r2];
            {
                float a0 = 0.f, a1 = 0.f, a2 = 0.f;
                const float* f0 = &fcw_s[r0][0];
                const float* f1 = &fcw_s[r1][0];
                const float* f2 = &fcw_s[r2][0];
                #pragma unroll
                for (int q = 0; q < 5; ++q) {
                    f32x4 hq = LD4(hv + 4 * q);
                    f32x4 g0 = LD4(f0 + 4 * q);
                    f32x4 g1 = LD4(f1 + 4 * q);
                    f32x4 g2 = LD4(f2 + 4 * q);
                    FMA4(a0, g0, hq) FMA4(a1, g1, hq) FMA4(a2, g2, hq)
                }
                d0 += a0; d1 += a1; d2 += a2;
            }
            const float lw0 = l2w_s[r0], lw1 = l2w_s[r1];
            const float lw2 = w3 ? l2w_s[r2] : 0.f;   // jo>=4 rows duplicated
            p_buf[cur][bs][jo] = lw0 * fmaxf(d0, 0.f) + lw1 * fmaxf(d1, 0.f)
                               + lw2 * fmaxf(d2, 0.f);
        }

        // ---- head stage 2: th2 = c-11 (sum 8 partials, store) ----
        const int th2 = c - NW - 1;
        if ((unsigned)th2 < (unsigned)T_ && w == hw2 && lane < NB) {
            const float* pp = &p_buf[prv][lane][0];
            f32x4 q0 = LD4(pp), q1 = LD4(pp + 4);
            float s = l2b_s + ((q0[0] + q0[1]) + (q0[2] + q0[3]))
                            + ((q1[0] + q1[1]) + (q1[2] + q1[3]));
            out[(size_t)(blockIdx.x * NB + lane) * T_ + th2] = s;
        }

        __syncthreads();  // publish cur writes; protect prv for next diagonal
    }
}

}  // namespace

extern "C" void kernel_launch(void* const* d_in, const int* in_sizes, int n_in,
                              void* d_out, int out_size, void* d_ws, size_t ws_size,
                              hipStream_t stream) {
    const float* x     = (const float*)d_in[0];
    const float* w_ih0 = (const float*)d_in[1];
    const float* w_ih  = (const float*)d_in[2];
    const float* w_hh  = (const float*)d_in[3];
    const float* b_ih  = (const float*)d_in[4];
    const float* b_hh  = (const float*)d_in[5];
    const float* fc_w  = (const float*)d_in[6];
    const float* fc_b  = (const float*)d_in[7];
    const float* l2_w  = (const float*)d_in[8];
    const float* l2_b  = (const float*)d_in[9];
    float* out = (float*)d_out;

    const int grid = B_ / NB;  // 256 = one block per CU
    hipLaunchKernelGGL(rnn_wavefront, dim3(grid), dim3(NTHR), 0, stream,
                       x, w_ih0, w_ih, w_hh, b_ih, b_hh, fc_w, fc_b,
                       l2_w, l2_b, out);
}